// Round 1
// baseline (405.967 us; speedup 1.0000x reference)
//
#include <hip/hip_runtime.h>
#include <math.h>

#define NN 50000
#define NE 800000
#define NG 64

// ws layout (float offsets)
#define WS_C     0                    // 8 floats: [h*4 + {att.Wl, att.Wr, att.We, att.B}]
#define WS_AMAX  16                   // 2*NN ordered-int max keys
#define WS_DENOM (WS_AMAX + 2*NN)     // 2*NN floats
#define WS_T1    (WS_DENOM + 2*NN)    // 2*NN floats
#define WS_BNSUM (WS_T1 + 2*NN)       // 128
#define WS_BNSQ  (WS_BNSUM + 128)     // 128
#define WS_SCORE (WS_BNSUM + 256)     // 2*NE floats, layout [e][h]

static_assert(NE % 4 == 0, "edge unroll");

__device__ __forceinline__ int f2ord(float f) {
  int i = __float_as_int(f);
  return i >= 0 ? i : (i ^ 0x7fffffff);   // monotone float->int map
}
__device__ __forceinline__ float ord2f(int k) {
  return __int_as_float(k >= 0 ? k : (k ^ 0x7fffffff));
}

extern "C" __global__ __launch_bounds__(256)
void k0_init(float* __restrict__ ws,
             const float* __restrict__ att, const float* __restrict__ Wl,
             const float* __restrict__ Wr, const float* __restrict__ We,
             const float* __restrict__ bl, const float* __restrict__ br,
             float* __restrict__ out)
{
  int tid = blockIdx.x * 256 + threadIdx.x;
  int nt = gridDim.x * 256;
  int* amax = (int*)(ws + WS_AMAX);
  for (int i = tid; i < 2 * NN; i += nt) amax[i] = (int)0x80000000;
  for (int i = tid; i < 2 * NN; i += nt) { ws[WS_DENOM + i] = 0.f; ws[WS_T1 + i] = 0.f; }
  for (int i = tid; i < 256; i += nt) ws[WS_BNSUM + i] = 0.f;
  for (int i = tid; i < NG * 128; i += nt) out[i] = 0.f;
  if (blockIdx.x == 0) {
    __shared__ float red[4][256];
    int t = threadIdx.x;                    // t = h*128 + d
    float a = att[t];
    red[0][t] = a * Wl[t];
    red[1][t] = a * Wr[t];
    red[2][t] = a * We[t];
    red[3][t] = a * (bl[t] + br[t]);
    __syncthreads();
    if (t < 8) {
      int k = t >> 1, h = t & 1;
      float s = 0.f;
      for (int d = 0; d < 128; ++d) s += red[k][h * 128 + d];
      ws[WS_C + h * 4 + k] = s;
    }
  }
}

// K1: per-edge attention logits. 4 edges/thread, weights staged in LDS.
// score_h = 0.6*(C·[xs,xd,ae,1]) + 0.4*Σ_d att_d*|Wl_d*xs + Wr_d*xd + We_d*ae + B_d|
extern "C" __global__ __launch_bounds__(256)
void k1_score(const int* __restrict__ ei, const float* __restrict__ x,
              const float* __restrict__ eattr,
              const float* __restrict__ Wl, const float* __restrict__ Wr,
              const float* __restrict__ We, const float* __restrict__ bl,
              const float* __restrict__ br, const float* __restrict__ att,
              float* __restrict__ ws)
{
  __shared__ __align__(16) float sWl[256], sWr[256], sWe[256], sB[256], sAt[256];
  int t = threadIdx.x;
  sWl[t] = Wl[t]; sWr[t] = Wr[t]; sWe[t] = We[t];
  sB[t] = bl[t] + br[t]; sAt[t] = att[t];
  __syncthreads();
  int base = (blockIdx.x * 256 + t) * 4;
  if (base >= NE) return;
  const int* __restrict__ srcs = ei;
  const int* __restrict__ dsts = ei + NE;
  int4 s4 = *(const int4*)&srcs[base];
  int4 dd4 = *(const int4*)&dsts[base];
  float4 ae4 = *(const float4*)&eattr[base];
  float xs0 = x[s4.x], xs1 = x[s4.y], xs2 = x[s4.z], xs3 = x[s4.w];
  float xd0 = x[dd4.x], xd1 = x[dd4.y], xd2 = x[dd4.z], xd3 = x[dd4.w];
  float ae0 = ae4.x, ae1 = ae4.y, ae2 = ae4.z, ae3 = ae4.w;

  float a00 = 0.f, a01 = 0.f, a02 = 0.f, a03 = 0.f;  // head0, edges 0..3
  float a10 = 0.f, a11 = 0.f, a12 = 0.f, a13 = 0.f;  // head1

#define STEP(wl_, wr_, we_, bb_, at_, xs_, xd_, ae_, acc_)                 \
  { float tt = fmaf(we_, ae_, bb_); tt = fmaf(wr_, xd_, tt);               \
    tt = fmaf(wl_, xs_, tt); acc_ = fmaf(fabsf(tt), at_, acc_); }

#define STEP4(c, q0, q1, q2, q3)                                           \
  STEP(wl.c, wr.c, we.c, bb.c, at.c, xs0, xd0, ae0, q0)                    \
  STEP(wl.c, wr.c, we.c, bb.c, at.c, xs1, xd1, ae1, q1)                    \
  STEP(wl.c, wr.c, we.c, bb.c, at.c, xs2, xd2, ae2, q2)                    \
  STEP(wl.c, wr.c, we.c, bb.c, at.c, xs3, xd3, ae3, q3)

#pragma unroll 2
  for (int j = 0; j < 128; j += 4) {
    float4 wl = *(const float4*)&sWl[j];
    float4 wr = *(const float4*)&sWr[j];
    float4 we = *(const float4*)&sWe[j];
    float4 bb = *(const float4*)&sB[j];
    float4 at = *(const float4*)&sAt[j];
    STEP4(x, a00, a01, a02, a03)
    STEP4(y, a00, a01, a02, a03)
    STEP4(z, a00, a01, a02, a03)
    STEP4(w, a00, a01, a02, a03)
  }
#pragma unroll 2
  for (int j = 128; j < 256; j += 4) {
    float4 wl = *(const float4*)&sWl[j];
    float4 wr = *(const float4*)&sWr[j];
    float4 we = *(const float4*)&sWe[j];
    float4 bb = *(const float4*)&sB[j];
    float4 at = *(const float4*)&sAt[j];
    STEP4(x, a10, a11, a12, a13)
    STEP4(y, a10, a11, a12, a13)
    STEP4(z, a10, a11, a12, a13)
    STEP4(w, a10, a11, a12, a13)
  }
#undef STEP4
#undef STEP

  float4 c0 = *(const float4*)&ws[WS_C];       // head0 linear-part dots
  float4 c1 = *(const float4*)&ws[WS_C + 4];   // head1
  int* amax = (int*)(ws + WS_AMAX);

#define EPI(eoff, xs_, xd_, ae_, accA, accB, dsti, out0, out1)             \
  { float lin0 = fmaf(c0.x, xs_, fmaf(c0.y, xd_, fmaf(c0.z, ae_, c0.w))); \
    out0 = 0.6f * lin0 + 0.4f * accA;                                      \
    float lin1 = fmaf(c1.x, xs_, fmaf(c1.y, xd_, fmaf(c1.z, ae_, c1.w))); \
    out1 = 0.6f * lin1 + 0.4f * accB;                                      \
    atomicMax(&amax[2 * dsti], f2ord(out0));                               \
    atomicMax(&amax[2 * dsti + 1], f2ord(out1)); }

  float sA0, sB0, sA1, sB1, sA2, sB2, sA3, sB3;
  EPI(0, xs0, xd0, ae0, a00, a10, dd4.x, sA0, sB0)
  EPI(1, xs1, xd1, ae1, a01, a11, dd4.y, sA1, sB1)
  EPI(2, xs2, xd2, ae2, a02, a12, dd4.z, sA2, sB2)
  EPI(3, xs3, xd3, ae3, a03, a13, dd4.w, sA3, sB3)
#undef EPI
  float4 st0 = {sA0, sB0, sA1, sB1};
  float4 st1 = {sA2, sB2, sA3, sB3};
  *(float4*)&ws[WS_SCORE + 2 * base] = st0;
  *(float4*)&ws[WS_SCORE + 2 * base + 4] = st1;
}

// K2: ea = exp(score - amax[dst]); accumulate denom and T1 = Σ ea*x_src
extern "C" __global__ __launch_bounds__(256)
void k2_accum(const int* __restrict__ ei, const float* __restrict__ x,
              float* __restrict__ ws)
{
  int e = blockIdx.x * 256 + threadIdx.x;
  if (e >= NE) return;
  int s = ei[e];
  int d = ei[NE + e];
  float xs = x[s];
  float2 sc = *(const float2*)&ws[WS_SCORE + 2 * e];
  const int* amax = (const int*)(ws + WS_AMAX);
  int2 kk = *(const int2*)&amax[2 * d];
  float ea0 = __expf(sc.x - ord2f(kk.x));
  float ea1 = __expf(sc.y - ord2f(kk.y));
  atomicAdd(&ws[WS_DENOM + 2 * d], ea0);
  atomicAdd(&ws[WS_DENOM + 2 * d + 1], ea1);
  atomicAdd(&ws[WS_T1 + 2 * d], ea0 * xs);
  atomicAdd(&ws[WS_T1 + 2 * d + 1], ea1 * xs);
}

// out[n,d] from the 4 per-node scalars (rank-1 aggregation)
__device__ __forceinline__ float node_out(const float* ws, int n,
                                          float wl0, float wl1, float b0, float b1,
                                          float bs)
{
  float2 den = *(const float2*)&ws[WS_DENOM + 2 * n];
  float2 t1v = *(const float2*)&ws[WS_T1 + 2 * n];
  float r0 = 1.f / (den.x + 1e-16f);
  float r1 = 1.f / (den.y + 1e-16f);
  return 0.5f * (fmaf(wl0, t1v.x * r0, b0 * (den.x * r0)) +
                 fmaf(wl1, t1v.y * r1, b1 * (den.y * r1))) + bs;
}

// K3: BN statistics (sum, sumsq per channel over nodes)
extern "C" __global__ __launch_bounds__(256)
void k3_stats(const float* __restrict__ Wl, const float* __restrict__ bl,
              const float* __restrict__ bias, float* __restrict__ ws)
{
  int d = threadIdx.x & 127;
  int row = threadIdx.x >> 7;
  float wl0 = Wl[d], wl1 = Wl[128 + d];
  float b0 = bl[d], b1 = bl[128 + d];
  float bs = bias[d];
  float sum = 0.f, sq = 0.f;
  for (int n = blockIdx.x * 2 + row; n < NN; n += gridDim.x * 2) {
    float o = node_out(ws, n, wl0, wl1, b0, b1, bs);
    sum += o;
    sq = fmaf(o, o, sq);
  }
  __shared__ float l1[256], l2[256];
  l1[threadIdx.x] = sum; l2[threadIdx.x] = sq;
  __syncthreads();
  if (row == 0) {
    atomicAdd(&ws[WS_BNSUM + d], l1[d] + l1[128 + d]);
    atomicAdd(&ws[WS_BNSQ + d], l2[d] + l2[128 + d]);
  }
}

// K4: apply BN + leaky_relu(0.01), pool into [G,128] via LDS (batch sorted)
extern "C" __global__ __launch_bounds__(256)
void k4_pool(const int* __restrict__ batch,
             const float* __restrict__ Wl, const float* __restrict__ bl,
             const float* __restrict__ bias, const float* __restrict__ gamma,
             const float* __restrict__ beta,
             float* __restrict__ ws, float* __restrict__ out)
{
  const int CHUNK = (NN + (int)gridDim.x - 1) / (int)gridDim.x;
  int n0 = blockIdx.x * CHUNK;
  if (n0 >= NN) return;
  int n1 = n0 + CHUNK; if (n1 > NN) n1 = NN;
  int d = threadIdx.x & 127;
  int row = threadIdx.x >> 7;
  const float invN = 1.f / (float)NN;
  float mean = ws[WS_BNSUM + d] * invN;
  float var = fmaf(ws[WS_BNSQ + d], invN, -mean * mean);
  float scale = gamma[d] * rsqrtf(var + 1e-5f);
  float shift = fmaf(-mean, scale, beta[d]);
  float wl0 = Wl[d], wl1 = Wl[128 + d];
  float b0 = bl[d], b1 = bl[128 + d];
  float bs = bias[d];
  __shared__ float pool[4][128];
  for (int i = threadIdx.x; i < 512; i += 256) ((float*)pool)[i] = 0.f;
  __syncthreads();
  int g0 = batch[n0];
  for (int n = n0 + row; n < n1; n += 2) {
    float o = node_out(ws, n, wl0, wl1, b0, b1, bs);
    float v = fmaf(o, scale, shift);
    v = v > 0.f ? v : 0.01f * v;
    int g = batch[n];
    int slot = g - g0;                    // >= 0: batch is sorted
    if (slot < 4) atomicAdd(&pool[slot][d], v);
    else atomicAdd(&out[g * 128 + d], v); // >4 graphs in chunk: rare fallback
  }
  __syncthreads();
  for (int i = threadIdx.x; i < 512; i += 256) {
    int slot = i >> 7, dd = i & 127;
    int g = g0 + slot;
    float v = pool[slot][dd];
    if (g < NG && v != 0.f) atomicAdd(&out[g * 128 + dd], v);
  }
}

extern "C" void kernel_launch(void* const* d_in, const int* in_sizes, int n_in,
                              void* d_out, int out_size, void* d_ws, size_t ws_size,
                              hipStream_t stream) {
  const float* x     = (const float*)d_in[0];
  const int*   ei    = (const int*)d_in[1];
  const float* eattr = (const float*)d_in[2];
  const int*   batch = (const int*)d_in[3];
  const float* Wl    = (const float*)d_in[4];
  const float* bl    = (const float*)d_in[5];
  const float* Wr    = (const float*)d_in[6];
  const float* br    = (const float*)d_in[7];
  const float* We    = (const float*)d_in[8];
  const float* att   = (const float*)d_in[9];
  const float* bias  = (const float*)d_in[10];
  const float* gam   = (const float*)d_in[11];
  const float* bet   = (const float*)d_in[12];
  float* ws  = (float*)d_ws;
  float* out = (float*)d_out;

  hipLaunchKernelGGL(k0_init, dim3(256), dim3(256), 0, stream,
                     ws, att, Wl, Wr, We, bl, br, out);
  hipLaunchKernelGGL(k1_score, dim3((NE / 4 + 255) / 256), dim3(256), 0, stream,
                     ei, x, eattr, Wl, Wr, We, bl, br, att, ws);
  hipLaunchKernelGGL(k2_accum, dim3((NE + 255) / 256), dim3(256), 0, stream,
                     ei, x, ws);
  hipLaunchKernelGGL(k3_stats, dim3(256), dim3(256), 0, stream,
                     Wl, bl, bias, ws);
  hipLaunchKernelGGL(k4_pool, dim3(256), dim3(256), 0, stream,
                     batch, Wl, bl, bias, gam, bet, ws, out);
}

// Round 2
// 312.761 us; speedup vs baseline: 1.2980x; 1.2980x over previous
//
#include <hip/hip_runtime.h>
#include <math.h>

#define NN 50000
#define NE 800000
#define NG 64

// ---------------- ws layout (float offsets) ----------------
// Common: C constants + per-node accumulators + BN scratch
#define WS_C     0                       // 8 floats: [h*4 + {att.Wl, att.Wr, att.We, att.B}]
#define WS_ACC   16                      // 4*NN floats: {den0,den1,t10,t11} per node (float4)
#define WS_BNSUM (WS_ACC + 4*NN)         // 128
#define WS_BNSQ  (WS_BNSUM + 128)        // 128
// CSR path only:
#define WS_CNT   (WS_BNSQ + 128)         // NN u32
#define WS_OFF   (WS_CNT + NN)           // NN+1 u32
#define WS_SLOT  (WS_OFF + NN + 4)       // NE u32  (pad keeps 16B alignment downstream)
#define WS_BPAY  (WS_SLOT + NE)          // NE float4 = {sc0, sc1, x_src, pad}
#define WS_END   (WS_BPAY + 4*NE)
#define WS_NEED_BYTES ((size_t)WS_END * 4 + 256)

static_assert((WS_BPAY % 4) == 0, "bpay 16B alignment");
static_assert(NE % 4 == 0, "edge unroll");

// ---------------- k0: init + attention-dot constants ----------------
extern "C" __global__ __launch_bounds__(256)
void k0_init(float* __restrict__ ws,
             const float* __restrict__ att, const float* __restrict__ Wl,
             const float* __restrict__ Wr, const float* __restrict__ We,
             const float* __restrict__ bl, const float* __restrict__ br,
             float* __restrict__ out, int zero_cnt)
{
  int tid = blockIdx.x * 256 + threadIdx.x;
  int nt = gridDim.x * 256;
  for (int i = tid; i < 4 * NN; i += nt) ws[WS_ACC + i] = 0.f;
  for (int i = tid; i < 256; i += nt) ws[WS_BNSUM + i] = 0.f;
  for (int i = tid; i < NG * 128; i += nt) out[i] = 0.f;
  if (zero_cnt) {
    unsigned* cnt = (unsigned*)(ws + WS_CNT);
    for (int i = tid; i < NN; i += nt) cnt[i] = 0u;
  }
  if (blockIdx.x == 0) {
    __shared__ float red[4][256];
    int t = threadIdx.x;                    // t = h*128 + d
    float a = att[t];
    red[0][t] = a * Wl[t];
    red[1][t] = a * Wr[t];
    red[2][t] = a * We[t];
    red[3][t] = a * (bl[t] + br[t]);
    __syncthreads();
    if (t < 8) {
      int k = t >> 1, h = t & 1;
      float s = 0.f;
      for (int d = 0; d < 128; ++d) s += red[k][h * 128 + d];
      ws[WS_C + h * 4 + k] = s;
    }
  }
}

// ---------------- ka: count in-degree, record slot (1 atomic/edge) ----------------
extern "C" __global__ __launch_bounds__(256)
void ka_count(const int* __restrict__ ei, float* __restrict__ ws)
{
  int base = (blockIdx.x * 256 + threadIdx.x) * 4;
  if (base >= NE) return;
  unsigned* cnt = (unsigned*)(ws + WS_CNT);
  unsigned* slot = (unsigned*)(ws + WS_SLOT);
  int4 d4 = *(const int4*)&ei[NE + base];
  uint4 s;
  s.x = atomicAdd(&cnt[d4.x], 1u);
  s.y = atomicAdd(&cnt[d4.y], 1u);
  s.z = atomicAdd(&cnt[d4.z], 1u);
  s.w = atomicAdd(&cnt[d4.w], 1u);
  *(uint4*)&slot[base] = s;
}

// ---------------- kb: exclusive scan of cnt -> off (single block) ----------------
extern "C" __global__ __launch_bounds__(1024)
void kb_scan(float* __restrict__ ws)
{
  const unsigned* cnt = (const unsigned*)(ws + WS_CNT);
  unsigned* off = (unsigned*)(ws + WS_OFF);
  __shared__ unsigned part[1024];
  int t = threadIdx.x;
  const int CH = (NN + 1023) / 1024;   // 49
  int lo = t * CH, hi = lo + CH; if (hi > NN) hi = NN; if (lo > NN) lo = NN;
  unsigned s = 0;
  for (int i = lo; i < hi; ++i) s += cnt[i];
  part[t] = s;
  __syncthreads();
  for (int d = 1; d < 1024; d <<= 1) {
    unsigned v = (t >= d) ? part[t - d] : 0u;
    __syncthreads();
    part[t] += v;
    __syncthreads();
  }
  unsigned run = part[t] - s;          // exclusive prefix
  for (int i = lo; i < hi; ++i) { off[i] = run; run += cnt[i]; }
  if (t == 1023) off[NN] = run;        // == NE
}

// ---------------- shared score machinery ----------------
// score_h = 0.6*(C·[xs,xd,ae,1]) + 0.4*Σ_d att_d*|Wl_d*xs + Wr_d*xd + We_d*ae + B_d|
#define STEP(wl_, wr_, we_, bb_, at_, xs_, xd_, ae_, acc_)                 \
  { float tt = fmaf(we_, ae_, bb_); tt = fmaf(wr_, xd_, tt);               \
    tt = fmaf(wl_, xs_, tt); acc_ = fmaf(fabsf(tt), at_, acc_); }

#define STEP4(c, q0, q1, q2, q3)                                           \
  STEP(wl.c, wr.c, we.c, bb.c, at.c, xs0, xd0, ae0, q0)                    \
  STEP(wl.c, wr.c, we.c, bb.c, at.c, xs1, xd1, ae1, q1)                    \
  STEP(wl.c, wr.c, we.c, bb.c, at.c, xs2, xd2, ae2, q2)                    \
  STEP(wl.c, wr.c, we.c, bb.c, at.c, xs3, xd3, ae3, q3)

#define SCORE_PREAMBLE                                                     \
  __shared__ __align__(16) float sWl[256], sWr[256], sWe[256], sB[256], sAt[256]; \
  { int t = threadIdx.x;                                                   \
    sWl[t] = Wl[t]; sWr[t] = Wr[t]; sWe[t] = We[t];                        \
    sB[t] = bl[t] + br[t]; sAt[t] = att[t]; }                              \
  __syncthreads();                                                         \
  int base = (blockIdx.x * 256 + threadIdx.x) * 4;                         \
  if (base >= NE) return;                                                  \
  int4 s4 = *(const int4*)&ei[base];                                       \
  int4 dd4 = *(const int4*)&ei[NE + base];                                 \
  float4 ae4 = *(const float4*)&eattr[base];                               \
  float xs0 = x[s4.x], xs1 = x[s4.y], xs2 = x[s4.z], xs3 = x[s4.w];        \
  float xd0 = x[dd4.x], xd1 = x[dd4.y], xd2 = x[dd4.z], xd3 = x[dd4.w];    \
  float ae0 = ae4.x, ae1 = ae4.y, ae2 = ae4.z, ae3 = ae4.w;                \
  float a00 = 0.f, a01 = 0.f, a02 = 0.f, a03 = 0.f;                        \
  float a10 = 0.f, a11 = 0.f, a12 = 0.f, a13 = 0.f;                        \
  _Pragma("unroll 2")                                                      \
  for (int j = 0; j < 128; j += 4) {                                       \
    float4 wl = *(const float4*)&sWl[j];                                   \
    float4 wr = *(const float4*)&sWr[j];                                   \
    float4 we = *(const float4*)&sWe[j];                                   \
    float4 bb = *(const float4*)&sB[j];                                    \
    float4 at = *(const float4*)&sAt[j];                                   \
    STEP4(x, a00, a01, a02, a03)                                           \
    STEP4(y, a00, a01, a02, a03)                                           \
    STEP4(z, a00, a01, a02, a03)                                           \
    STEP4(w, a00, a01, a02, a03)                                           \
  }                                                                        \
  _Pragma("unroll 2")                                                      \
  for (int j = 128; j < 256; j += 4) {                                     \
    float4 wl = *(const float4*)&sWl[j];                                   \
    float4 wr = *(const float4*)&sWr[j];                                   \
    float4 we = *(const float4*)&sWe[j];                                   \
    float4 bb = *(const float4*)&sB[j];                                    \
    float4 at = *(const float4*)&sAt[j];                                   \
    STEP4(x, a10, a11, a12, a13)                                           \
    STEP4(y, a10, a11, a12, a13)                                           \
    STEP4(z, a10, a11, a12, a13)                                           \
    STEP4(w, a10, a11, a12, a13)                                           \
  }                                                                        \
  float4 c0 = *(const float4*)&ws[WS_C];                                   \
  float4 c1 = *(const float4*)&ws[WS_C + 4];

#define SCORES(xs_, xd_, ae_, accA, accB, out0, out1)                      \
  { float lin0 = fmaf(c0.x, xs_, fmaf(c0.y, xd_, fmaf(c0.z, ae_, c0.w))); \
    out0 = fmaf(0.4f, accA, 0.6f * lin0);                                  \
    float lin1 = fmaf(c1.x, xs_, fmaf(c1.y, xd_, fmaf(c1.z, ae_, c1.w))); \
    out1 = fmaf(0.4f, accB, 0.6f * lin1); }

// ---------------- kc: compute scores, place into CSR buckets (0 atomics) ----------------
extern "C" __global__ __launch_bounds__(256)
void kc_place(const int* __restrict__ ei, const float* __restrict__ x,
              const float* __restrict__ eattr,
              const float* __restrict__ Wl, const float* __restrict__ Wr,
              const float* __restrict__ We, const float* __restrict__ bl,
              const float* __restrict__ br, const float* __restrict__ att,
              float* __restrict__ ws)
{
  SCORE_PREAMBLE
  const unsigned* off = (const unsigned*)(ws + WS_OFF);
  const unsigned* slot = (const unsigned*)(ws + WS_SLOT);
  float4* bpay = (float4*)(ws + WS_BPAY);
  uint4 sl = *(const uint4*)&slot[base];
  float s0, s1;
  SCORES(xs0, xd0, ae0, a00, a10, s0, s1)
  bpay[off[dd4.x] + sl.x] = make_float4(s0, s1, xs0, 0.f);
  SCORES(xs1, xd1, ae1, a01, a11, s0, s1)
  bpay[off[dd4.y] + sl.y] = make_float4(s0, s1, xs1, 0.f);
  SCORES(xs2, xd2, ae2, a02, a12, s0, s1)
  bpay[off[dd4.z] + sl.z] = make_float4(s0, s1, xs2, 0.f);
  SCORES(xs3, xd3, ae3, a03, a13, s0, s1)
  bpay[off[dd4.w] + sl.w] = make_float4(s0, s1, xs3, 0.f);
}

// ---------------- kd: atomic-free gather per node (16 lanes/node) ----------------
extern "C" __global__ __launch_bounds__(256)
void kd_gather(float* __restrict__ ws)
{
  int n = blockIdx.x * 16 + (threadIdx.x >> 4);
  int lane = threadIdx.x & 15;
  if (n >= NN) return;
  const unsigned* off = (const unsigned*)(ws + WS_OFF);
  const unsigned* cnt = (const unsigned*)(ws + WS_CNT);
  const float4* bpay = (const float4*)(ws + WS_BPAY);
  unsigned o = off[n];
  unsigned c = cnt[n];
  float den0 = 0.f, den1 = 0.f, t10 = 0.f, t11 = 0.f;
  for (unsigned j = lane; j < c; j += 16) {
    float4 p = bpay[o + j];
    float e0 = __expf(p.x);
    float e1 = __expf(p.y);
    den0 += e0; den1 += e1;
    t10 = fmaf(e0, p.z, t10);
    t11 = fmaf(e1, p.z, t11);
  }
#pragma unroll
  for (int m = 8; m >= 1; m >>= 1) {
    den0 += __shfl_xor(den0, m, 16);
    den1 += __shfl_xor(den1, m, 16);
    t10  += __shfl_xor(t10, m, 16);
    t11  += __shfl_xor(t11, m, 16);
  }
  if (lane == 0)
    *(float4*)&ws[WS_ACC + 4 * n] = make_float4(den0, den1, t10, t11);
}

// ---------------- fallback: fused score + exp + 4 atomics/edge ----------------
extern "C" __global__ __launch_bounds__(256)
void k12f(const int* __restrict__ ei, const float* __restrict__ x,
          const float* __restrict__ eattr,
          const float* __restrict__ Wl, const float* __restrict__ Wr,
          const float* __restrict__ We, const float* __restrict__ bl,
          const float* __restrict__ br, const float* __restrict__ att,
          float* __restrict__ ws)
{
  SCORE_PREAMBLE
  float* acc = ws + WS_ACC;
  float s0, s1;
#define EPI(xs_, dsti, accA, accB)                                         \
  { SCORES(xs_, xs_ /*unused*/, 0.f /*unused*/, accA, accB, s0, s1) }
#undef EPI
#define EPI2(xs_, xd_, ae_, accA, accB, dsti)                              \
  { SCORES(xs_, xd_, ae_, accA, accB, s0, s1)                              \
    float e0 = __expf(s0), e1 = __expf(s1);                                \
    float* a = &acc[4 * dsti];                                             \
    atomicAdd(a + 0, e0); atomicAdd(a + 1, e1);                            \
    atomicAdd(a + 2, e0 * xs_); atomicAdd(a + 3, e1 * xs_); }
  EPI2(xs0, xd0, ae0, a00, a10, dd4.x)
  EPI2(xs1, xd1, ae1, a01, a11, dd4.y)
  EPI2(xs2, xd2, ae2, a02, a12, dd4.z)
  EPI2(xs3, xd3, ae3, a03, a13, dd4.w)
#undef EPI2
}

// ---------------- node output from the 4 per-node scalars ----------------
__device__ __forceinline__ float node_out4(float4 a, float wl0, float wl1,
                                           float b0, float b1, float bs)
{
  float r0 = 1.f / (a.x + 1e-16f);
  float r1 = 1.f / (a.y + 1e-16f);
  return 0.5f * (fmaf(wl0, a.z * r0, b0 * (a.x * r0)) +
                 fmaf(wl1, a.w * r1, b1 * (a.y * r1))) + bs;
}

// ---------------- k3: BN statistics ----------------
extern "C" __global__ __launch_bounds__(256)
void k3_stats(const float* __restrict__ Wl, const float* __restrict__ bl,
              const float* __restrict__ bias, float* __restrict__ ws)
{
  int d = threadIdx.x & 127;
  int row = threadIdx.x >> 7;
  float wl0 = Wl[d], wl1 = Wl[128 + d];
  float b0 = bl[d], b1 = bl[128 + d];
  float bs = bias[d];
  float sum = 0.f, sq = 0.f;
  for (int n = blockIdx.x * 2 + row; n < NN; n += gridDim.x * 2) {
    float4 a = *(const float4*)&ws[WS_ACC + 4 * n];
    float o = node_out4(a, wl0, wl1, b0, b1, bs);
    sum += o;
    sq = fmaf(o, o, sq);
  }
  __shared__ float l1[256], l2[256];
  l1[threadIdx.x] = sum; l2[threadIdx.x] = sq;
  __syncthreads();
  if (row == 0) {
    atomicAdd(&ws[WS_BNSUM + d], l1[d] + l1[128 + d]);
    atomicAdd(&ws[WS_BNSQ + d], l2[d] + l2[128 + d]);
  }
}

// ---------------- k4: BN apply + leaky_relu + graph pooling ----------------
extern "C" __global__ __launch_bounds__(256)
void k4_pool(const int* __restrict__ batch,
             const float* __restrict__ Wl, const float* __restrict__ bl,
             const float* __restrict__ bias, const float* __restrict__ gamma,
             const float* __restrict__ beta,
             float* __restrict__ ws, float* __restrict__ out)
{
  const int CHUNK = (NN + (int)gridDim.x - 1) / (int)gridDim.x;
  int n0 = blockIdx.x * CHUNK;
  if (n0 >= NN) return;
  int n1 = n0 + CHUNK; if (n1 > NN) n1 = NN;
  int d = threadIdx.x & 127;
  int row = threadIdx.x >> 7;
  const float invN = 1.f / (float)NN;
  float mean = ws[WS_BNSUM + d] * invN;
  float var = fmaf(ws[WS_BNSQ + d], invN, -mean * mean);
  float scale = gamma[d] * rsqrtf(var + 1e-5f);
  float shift = fmaf(-mean, scale, beta[d]);
  float wl0 = Wl[d], wl1 = Wl[128 + d];
  float b0 = bl[d], b1 = bl[128 + d];
  float bs = bias[d];
  __shared__ float pool[4][128];
  for (int i = threadIdx.x; i < 512; i += 256) ((float*)pool)[i] = 0.f;
  __syncthreads();
  int g0 = batch[n0];
  for (int n = n0 + row; n < n1; n += 2) {
    float4 a = *(const float4*)&ws[WS_ACC + 4 * n];
    float o = node_out4(a, wl0, wl1, b0, b1, bs);
    float v = fmaf(o, scale, shift);
    v = v > 0.f ? v : 0.01f * v;
    int g = batch[n];
    int slot = g - g0;                    // >= 0: batch is sorted
    if (slot < 4) atomicAdd(&pool[slot][d], v);
    else atomicAdd(&out[g * 128 + d], v); // >4 graphs in chunk: rare fallback
  }
  __syncthreads();
  for (int i = threadIdx.x; i < 512; i += 256) {
    int slot = i >> 7, dd = i & 127;
    int g = g0 + slot;
    float v = pool[slot][dd];
    if (g < NG && v != 0.f) atomicAdd(&out[g * 128 + dd], v);
  }
}

extern "C" void kernel_launch(void* const* d_in, const int* in_sizes, int n_in,
                              void* d_out, int out_size, void* d_ws, size_t ws_size,
                              hipStream_t stream) {
  const float* x     = (const float*)d_in[0];
  const int*   ei    = (const int*)d_in[1];
  const float* eattr = (const float*)d_in[2];
  const int*   batch = (const int*)d_in[3];
  const float* Wl    = (const float*)d_in[4];
  const float* bl    = (const float*)d_in[5];
  const float* Wr    = (const float*)d_in[6];
  const float* br    = (const float*)d_in[7];
  const float* We    = (const float*)d_in[8];
  const float* att   = (const float*)d_in[9];
  const float* bias  = (const float*)d_in[10];
  const float* gam   = (const float*)d_in[11];
  const float* bet   = (const float*)d_in[12];
  float* ws  = (float*)d_ws;
  float* out = (float*)d_out;

  const bool csr = (ws_size >= WS_NEED_BYTES);
  const int EB = (NE / 4 + 255) / 256;   // edge blocks (4 edges/thread)

  hipLaunchKernelGGL(k0_init, dim3(256), dim3(256), 0, stream,
                     ws, att, Wl, Wr, We, bl, br, out, csr ? 1 : 0);
  if (csr) {
    hipLaunchKernelGGL(ka_count, dim3(EB), dim3(256), 0, stream, ei, ws);
    hipLaunchKernelGGL(kb_scan, dim3(1), dim3(1024), 0, stream, ws);
    hipLaunchKernelGGL(kc_place, dim3(EB), dim3(256), 0, stream,
                       ei, x, eattr, Wl, Wr, We, bl, br, att, ws);
    hipLaunchKernelGGL(kd_gather, dim3((NN + 15) / 16), dim3(256), 0, stream, ws);
  } else {
    hipLaunchKernelGGL(k12f, dim3(EB), dim3(256), 0, stream,
                       ei, x, eattr, Wl, Wr, We, bl, br, att, ws);
  }
  hipLaunchKernelGGL(k3_stats, dim3(256), dim3(256), 0, stream,
                     Wl, bl, bias, ws);
  hipLaunchKernelGGL(k4_pool, dim3(256), dim3(256), 0, stream,
                     batch, Wl, bl, bias, gam, bet, ws, out);
}

// Round 3
// 242.670 us; speedup vs baseline: 1.6729x; 1.2888x over previous
//
#include <hip/hip_runtime.h>
#include <math.h>

#define NN 50000
#define NE 800000
#define NG 64

// ---------------- ws layout (float offsets) ----------------
#define WS_C     0                       // 8 floats: [h*4 + {att.Wl, att.Wr, att.We, att.B}]
#define WS_ACC   16                      // 4*NN floats: {den0,den1,t10,t11} per node (float4)
#define WS_BNSUM (WS_ACC + 4*NN)         // 128
#define WS_BNSQ  (WS_BNSUM + 128)        // 128
// CSR path only:
#define WS_CNT   (WS_BNSQ + 128)         // NN u32
#define WS_OFF   (WS_CNT + NN)           // NN+1 u32
#define WS_SLOT  (WS_OFF + NN + 4)       // NE u32
#define WS_BPAY  (WS_SLOT + NE)          // NE float4 = {sc0, sc1, x_src, pad}
#define WS_END   (WS_BPAY + 4*NE)
#define WS_NEED_BYTES ((size_t)WS_END * 4 + 256)

// scan decomposition: NN = SC_BLOCKS * SC_CHUNK exactly
#define SC_CHUNK  200
#define SC_BLOCKS 250
static_assert(SC_BLOCKS * SC_CHUNK == NN, "scan tiling");
static_assert((WS_BPAY % 4) == 0, "bpay 16B alignment");
static_assert(NE % 4 == 0, "edge unroll");

// ---------------- k0: init + attention-dot constants ----------------
extern "C" __global__ __launch_bounds__(256)
void k0_init(float* __restrict__ ws,
             const float* __restrict__ att, const float* __restrict__ Wl,
             const float* __restrict__ Wr, const float* __restrict__ We,
             const float* __restrict__ bl, const float* __restrict__ br,
             float* __restrict__ out, int zero_cnt)
{
  int tid = blockIdx.x * 256 + threadIdx.x;
  int nt = gridDim.x * 256;
  for (int i = tid; i < 4 * NN; i += nt) ws[WS_ACC + i] = 0.f;
  for (int i = tid; i < 256; i += nt) ws[WS_BNSUM + i] = 0.f;
  for (int i = tid; i < NG * 128; i += nt) out[i] = 0.f;
  if (zero_cnt) {
    unsigned* cnt = (unsigned*)(ws + WS_CNT);
    for (int i = tid; i < NN; i += nt) cnt[i] = 0u;
  }
  if (blockIdx.x == 0) {
    __shared__ float red[4][256];
    int t = threadIdx.x;                    // t = h*128 + d
    float a = att[t];
    red[0][t] = a * Wl[t];
    red[1][t] = a * Wr[t];
    red[2][t] = a * We[t];
    red[3][t] = a * (bl[t] + br[t]);
    __syncthreads();
    if (t < 8) {
      int k = t >> 1, h = t & 1;
      float s = 0.f;
      for (int d = 0; d < 128; ++d) s += red[k][h * 128 + d];
      ws[WS_C + h * 4 + k] = s;
    }
  }
}

// ---------------- ka: count in-degree, record slot (1 atomic/edge) ----------------
extern "C" __global__ __launch_bounds__(256)
void ka_count(const int* __restrict__ ei, float* __restrict__ ws)
{
  int base = (blockIdx.x * 256 + threadIdx.x) * 4;
  if (base >= NE) return;
  unsigned* cnt = (unsigned*)(ws + WS_CNT);
  unsigned* slot = (unsigned*)(ws + WS_SLOT);
  int4 d4 = *(const int4*)&ei[NE + base];
  uint4 s;
  s.x = atomicAdd(&cnt[d4.x], 1u);
  s.y = atomicAdd(&cnt[d4.y], 1u);
  s.z = atomicAdd(&cnt[d4.z], 1u);
  s.w = atomicAdd(&cnt[d4.w], 1u);
  *(uint4*)&slot[base] = s;
}

// ---------------- kb1: per-chunk block sums (blocksum stash in dead WS_BPAY head) ----------------
extern "C" __global__ __launch_bounds__(256)
void kb1_sum(float* __restrict__ ws)
{
  const unsigned* cnt = (const unsigned*)(ws + WS_CNT);
  unsigned* bsum = (unsigned*)(ws + WS_BPAY);     // first SC_BLOCKS u32, dead until kc
  __shared__ unsigned r[256];
  int t = threadIdx.x, b = blockIdx.x;
  unsigned v = (t < SC_CHUNK) ? cnt[b * SC_CHUNK + t] : 0u;
  r[t] = v;
  __syncthreads();
#pragma unroll
  for (int s = 128; s > 0; s >>= 1) {
    if (t < s) r[t] += r[t + s];
    __syncthreads();
  }
  if (t == 0) bsum[b] = r[0];
}

// ---------------- kb2: block base from scan of bsum + local exclusive scan -> off ----------------
extern "C" __global__ __launch_bounds__(256)
void kb2_off(float* __restrict__ ws)
{
  const unsigned* cnt = (const unsigned*)(ws + WS_CNT);
  const unsigned* bsum = (const unsigned*)(ws + WS_BPAY);
  unsigned* off = (unsigned*)(ws + WS_OFF);
  __shared__ unsigned sdat[256];
  int t = threadIdx.x, b = blockIdx.x;
  // phase 1: inclusive scan of the 250 block sums
  unsigned v = (t < SC_BLOCKS) ? bsum[t] : 0u;
  sdat[t] = v;
  __syncthreads();
#pragma unroll
  for (int d = 1; d < 256; d <<= 1) {
    unsigned u = (t >= d) ? sdat[t - d] : 0u;
    __syncthreads();
    sdat[t] += u;
    __syncthreads();
  }
  unsigned base = (b == 0) ? 0u : sdat[b - 1];
  __syncthreads();
  // phase 2: local exclusive scan of this block's 200 counts
  unsigned c = (t < SC_CHUNK) ? cnt[b * SC_CHUNK + t] : 0u;
  sdat[t] = c;
  __syncthreads();
#pragma unroll
  for (int d = 1; d < 256; d <<= 1) {
    unsigned u = (t >= d) ? sdat[t - d] : 0u;
    __syncthreads();
    sdat[t] += u;
    __syncthreads();
  }
  if (t < SC_CHUNK) off[b * SC_CHUNK + t] = base + (sdat[t] - c);
  if (b == SC_BLOCKS - 1 && t == SC_CHUNK - 1) off[NN] = NE;
}

// ---------------- shared score machinery ----------------
// score_h = 0.6*(C·[xs,xd,ae,1]) + 0.4*Σ_d att_d*|Wl_d*xs + Wr_d*xd + We_d*ae + B_d|
#define STEP(wl_, wr_, we_, bb_, at_, xs_, xd_, ae_, acc_)                 \
  { float tt = fmaf(we_, ae_, bb_); tt = fmaf(wr_, xd_, tt);               \
    tt = fmaf(wl_, xs_, tt); acc_ = fmaf(fabsf(tt), at_, acc_); }

#define STEP4(c, q0, q1, q2, q3)                                           \
  STEP(wl.c, wr.c, we.c, bb.c, at.c, xs0, xd0, ae0, q0)                    \
  STEP(wl.c, wr.c, we.c, bb.c, at.c, xs1, xd1, ae1, q1)                    \
  STEP(wl.c, wr.c, we.c, bb.c, at.c, xs2, xd2, ae2, q2)                    \
  STEP(wl.c, wr.c, we.c, bb.c, at.c, xs3, xd3, ae3, q3)

#define SCORE_PREAMBLE                                                     \
  __shared__ __align__(16) float sWl[256], sWr[256], sWe[256], sB[256], sAt[256]; \
  { int t = threadIdx.x;                                                   \
    sWl[t] = Wl[t]; sWr[t] = Wr[t]; sWe[t] = We[t];                        \
    sB[t] = bl[t] + br[t]; sAt[t] = att[t]; }                              \
  __syncthreads();                                                         \
  int base = (blockIdx.x * 256 + threadIdx.x) * 4;                         \
  if (base >= NE) return;                                                  \
  int4 s4 = *(const int4*)&ei[base];                                       \
  int4 dd4 = *(const int4*)&ei[NE + base];                                 \
  float4 ae4 = *(const float4*)&eattr[base];                               \
  float xs0 = x[s4.x], xs1 = x[s4.y], xs2 = x[s4.z], xs3 = x[s4.w];        \
  float xd0 = x[dd4.x], xd1 = x[dd4.y], xd2 = x[dd4.z], xd3 = x[dd4.w];    \
  float ae0 = ae4.x, ae1 = ae4.y, ae2 = ae4.z, ae3 = ae4.w;                \
  float a00 = 0.f, a01 = 0.f, a02 = 0.f, a03 = 0.f;                        \
  float a10 = 0.f, a11 = 0.f, a12 = 0.f, a13 = 0.f;                        \
  _Pragma("unroll 2")                                                      \
  for (int j = 0; j < 128; j += 4) {                                       \
    float4 wl = *(const float4*)&sWl[j];                                   \
    float4 wr = *(const float4*)&sWr[j];                                   \
    float4 we = *(const float4*)&sWe[j];                                   \
    float4 bb = *(const float4*)&sB[j];                                    \
    float4 at = *(const float4*)&sAt[j];                                   \
    STEP4(x, a00, a01, a02, a03)                                           \
    STEP4(y, a00, a01, a02, a03)                                           \
    STEP4(z, a00, a01, a02, a03)                                           \
    STEP4(w, a00, a01, a02, a03)                                           \
  }                                                                        \
  _Pragma("unroll 2")                                                      \
  for (int j = 128; j < 256; j += 4) {                                     \
    float4 wl = *(const float4*)&sWl[j];                                   \
    float4 wr = *(const float4*)&sWr[j];                                   \
    float4 we = *(const float4*)&sWe[j];                                   \
    float4 bb = *(const float4*)&sB[j];                                    \
    float4 at = *(const float4*)&sAt[j];                                   \
    STEP4(x, a10, a11, a12, a13)                                           \
    STEP4(y, a10, a11, a12, a13)                                           \
    STEP4(z, a10, a11, a12, a13)                                           \
    STEP4(w, a10, a11, a12, a13)                                           \
  }                                                                        \
  float4 c0 = *(const float4*)&ws[WS_C];                                   \
  float4 c1 = *(const float4*)&ws[WS_C + 4];

#define SCORES(xs_, xd_, ae_, accA, accB, out0, out1)                      \
  { float lin0 = fmaf(c0.x, xs_, fmaf(c0.y, xd_, fmaf(c0.z, ae_, c0.w))); \
    out0 = fmaf(0.4f, accA, 0.6f * lin0);                                  \
    float lin1 = fmaf(c1.x, xs_, fmaf(c1.y, xd_, fmaf(c1.z, ae_, c1.w))); \
    out1 = fmaf(0.4f, accB, 0.6f * lin1); }

// ---------------- kc: compute scores, place into CSR buckets (0 atomics) ----------------
extern "C" __global__ __launch_bounds__(256)
void kc_place(const int* __restrict__ ei, const float* __restrict__ x,
              const float* __restrict__ eattr,
              const float* __restrict__ Wl, const float* __restrict__ Wr,
              const float* __restrict__ We, const float* __restrict__ bl,
              const float* __restrict__ br, const float* __restrict__ att,
              float* __restrict__ ws)
{
  SCORE_PREAMBLE
  const unsigned* off = (const unsigned*)(ws + WS_OFF);
  const unsigned* slot = (const unsigned*)(ws + WS_SLOT);
  float4* bpay = (float4*)(ws + WS_BPAY);
  uint4 sl = *(const uint4*)&slot[base];
  float s0, s1;
  SCORES(xs0, xd0, ae0, a00, a10, s0, s1)
  bpay[off[dd4.x] + sl.x] = make_float4(s0, s1, xs0, 0.f);
  SCORES(xs1, xd1, ae1, a01, a11, s0, s1)
  bpay[off[dd4.y] + sl.y] = make_float4(s0, s1, xs1, 0.f);
  SCORES(xs2, xd2, ae2, a02, a12, s0, s1)
  bpay[off[dd4.z] + sl.z] = make_float4(s0, s1, xs2, 0.f);
  SCORES(xs3, xd3, ae3, a03, a13, s0, s1)
  bpay[off[dd4.w] + sl.w] = make_float4(s0, s1, xs3, 0.f);
}

// ---------------- kd: atomic-free gather per node (16 lanes/node) ----------------
extern "C" __global__ __launch_bounds__(256)
void kd_gather(float* __restrict__ ws)
{
  int n = blockIdx.x * 16 + (threadIdx.x >> 4);
  int lane = threadIdx.x & 15;
  if (n >= NN) return;
  const unsigned* off = (const unsigned*)(ws + WS_OFF);
  const unsigned* cnt = (const unsigned*)(ws + WS_CNT);
  const float4* bpay = (const float4*)(ws + WS_BPAY);
  unsigned o = off[n];
  unsigned c = cnt[n];
  float den0 = 0.f, den1 = 0.f, t10 = 0.f, t11 = 0.f;
  for (unsigned j = lane; j < c; j += 16) {
    float4 p = bpay[o + j];
    float e0 = __expf(p.x);
    float e1 = __expf(p.y);
    den0 += e0; den1 += e1;
    t10 = fmaf(e0, p.z, t10);
    t11 = fmaf(e1, p.z, t11);
  }
#pragma unroll
  for (int m = 8; m >= 1; m >>= 1) {
    den0 += __shfl_xor(den0, m, 16);
    den1 += __shfl_xor(den1, m, 16);
    t10  += __shfl_xor(t10, m, 16);
    t11  += __shfl_xor(t11, m, 16);
  }
  if (lane == 0)
    *(float4*)&ws[WS_ACC + 4 * n] = make_float4(den0, den1, t10, t11);
}

// ---------------- fallback: fused score + exp + 4 atomics/edge ----------------
extern "C" __global__ __launch_bounds__(256)
void k12f(const int* __restrict__ ei, const float* __restrict__ x,
          const float* __restrict__ eattr,
          const float* __restrict__ Wl, const float* __restrict__ Wr,
          const float* __restrict__ We, const float* __restrict__ bl,
          const float* __restrict__ br, const float* __restrict__ att,
          float* __restrict__ ws)
{
  SCORE_PREAMBLE
  float* acc = ws + WS_ACC;
  float s0, s1;
#define EPI2(xs_, xd_, ae_, accA, accB, dsti)                              \
  { SCORES(xs_, xd_, ae_, accA, accB, s0, s1)                              \
    float e0 = __expf(s0), e1 = __expf(s1);                                \
    float* a = &acc[4 * dsti];                                             \
    atomicAdd(a + 0, e0); atomicAdd(a + 1, e1);                            \
    atomicAdd(a + 2, e0 * xs_); atomicAdd(a + 3, e1 * xs_); }
  EPI2(xs0, xd0, ae0, a00, a10, dd4.x)
  EPI2(xs1, xd1, ae1, a01, a11, dd4.y)
  EPI2(xs2, xd2, ae2, a02, a12, dd4.z)
  EPI2(xs3, xd3, ae3, a03, a13, dd4.w)
#undef EPI2
}

// ---------------- node output from the 4 per-node scalars ----------------
__device__ __forceinline__ float node_out4(float4 a, float wl0, float wl1,
                                           float b0, float b1, float bs)
{
  float r0 = 1.f / (a.x + 1e-16f);
  float r1 = 1.f / (a.y + 1e-16f);
  return 0.5f * (fmaf(wl0, a.z * r0, b0 * (a.x * r0)) +
                 fmaf(wl1, a.w * r1, b1 * (a.y * r1))) + bs;
}

// ---------------- k3: BN statistics ----------------
extern "C" __global__ __launch_bounds__(256)
void k3_stats(const float* __restrict__ Wl, const float* __restrict__ bl,
              const float* __restrict__ bias, float* __restrict__ ws)
{
  int d = threadIdx.x & 127;
  int row = threadIdx.x >> 7;
  float wl0 = Wl[d], wl1 = Wl[128 + d];
  float b0 = bl[d], b1 = bl[128 + d];
  float bs = bias[d];
  float sum = 0.f, sq = 0.f;
  for (int n = blockIdx.x * 2 + row; n < NN; n += gridDim.x * 2) {
    float4 a = *(const float4*)&ws[WS_ACC + 4 * n];
    float o = node_out4(a, wl0, wl1, b0, b1, bs);
    sum += o;
    sq = fmaf(o, o, sq);
  }
  __shared__ float l1[256], l2[256];
  l1[threadIdx.x] = sum; l2[threadIdx.x] = sq;
  __syncthreads();
  if (row == 0) {
    atomicAdd(&ws[WS_BNSUM + d], l1[d] + l1[128 + d]);
    atomicAdd(&ws[WS_BNSQ + d], l2[d] + l2[128 + d]);
  }
}

// ---------------- k4: BN apply + leaky_relu + graph pooling ----------------
extern "C" __global__ __launch_bounds__(256)
void k4_pool(const int* __restrict__ batch,
             const float* __restrict__ Wl, const float* __restrict__ bl,
             const float* __restrict__ bias, const float* __restrict__ gamma,
             const float* __restrict__ beta,
             float* __restrict__ ws, float* __restrict__ out)
{
  const int CHUNK = (NN + (int)gridDim.x - 1) / (int)gridDim.x;
  int n0 = blockIdx.x * CHUNK;
  if (n0 >= NN) return;
  int n1 = n0 + CHUNK; if (n1 > NN) n1 = NN;
  int d = threadIdx.x & 127;
  int row = threadIdx.x >> 7;
  const float invN = 1.f / (float)NN;
  float mean = ws[WS_BNSUM + d] * invN;
  float var = fmaf(ws[WS_BNSQ + d], invN, -mean * mean);
  float scale = gamma[d] * rsqrtf(var + 1e-5f);
  float shift = fmaf(-mean, scale, beta[d]);
  float wl0 = Wl[d], wl1 = Wl[128 + d];
  float b0 = bl[d], b1 = bl[128 + d];
  float bs = bias[d];
  __shared__ float pool[4][128];
  for (int i = threadIdx.x; i < 512; i += 256) ((float*)pool)[i] = 0.f;
  __syncthreads();
  int g0 = batch[n0];
  for (int n = n0 + row; n < n1; n += 2) {
    float4 a = *(const float4*)&ws[WS_ACC + 4 * n];
    float o = node_out4(a, wl0, wl1, b0, b1, bs);
    float v = fmaf(o, scale, shift);
    v = v > 0.f ? v : 0.01f * v;
    int g = batch[n];
    int slot = g - g0;                    // >= 0: batch is sorted
    if (slot < 4) atomicAdd(&pool[slot][d], v);
    else atomicAdd(&out[g * 128 + d], v); // >4 graphs in chunk: rare fallback
  }
  __syncthreads();
  for (int i = threadIdx.x; i < 512; i += 256) {
    int slot = i >> 7, dd = i & 127;
    int g = g0 + slot;
    float v = pool[slot][dd];
    if (g < NG && v != 0.f) atomicAdd(&out[g * 128 + dd], v);
  }
}

extern "C" void kernel_launch(void* const* d_in, const int* in_sizes, int n_in,
                              void* d_out, int out_size, void* d_ws, size_t ws_size,
                              hipStream_t stream) {
  const float* x     = (const float*)d_in[0];
  const int*   ei    = (const int*)d_in[1];
  const float* eattr = (const float*)d_in[2];
  const int*   batch = (const int*)d_in[3];
  const float* Wl    = (const float*)d_in[4];
  const float* bl    = (const float*)d_in[5];
  const float* Wr    = (const float*)d_in[6];
  const float* br    = (const float*)d_in[7];
  const float* We    = (const float*)d_in[8];
  const float* att   = (const float*)d_in[9];
  const float* bias  = (const float*)d_in[10];
  const float* gam   = (const float*)d_in[11];
  const float* bet   = (const float*)d_in[12];
  float* ws  = (float*)d_ws;
  float* out = (float*)d_out;

  const bool csr = (ws_size >= WS_NEED_BYTES);
  const int EB = (NE / 4 + 255) / 256;   // edge blocks (4 edges/thread)

  hipLaunchKernelGGL(k0_init, dim3(256), dim3(256), 0, stream,
                     ws, att, Wl, Wr, We, bl, br, out, csr ? 1 : 0);
  if (csr) {
    hipLaunchKernelGGL(ka_count, dim3(EB), dim3(256), 0, stream, ei, ws);
    hipLaunchKernelGGL(kb1_sum, dim3(SC_BLOCKS), dim3(256), 0, stream, ws);
    hipLaunchKernelGGL(kb2_off, dim3(SC_BLOCKS), dim3(256), 0, stream, ws);
    hipLaunchKernelGGL(kc_place, dim3(EB), dim3(256), 0, stream,
                       ei, x, eattr, Wl, Wr, We, bl, br, att, ws);
    hipLaunchKernelGGL(kd_gather, dim3((NN + 15) / 16), dim3(256), 0, stream, ws);
  } else {
    hipLaunchKernelGGL(k12f, dim3(EB), dim3(256), 0, stream,
                       ei, x, eattr, Wl, Wr, We, bl, br, att, ws);
  }
  hipLaunchKernelGGL(k3_stats, dim3(256), dim3(256), 0, stream,
                     Wl, bl, bias, ws);
  hipLaunchKernelGGL(k4_pool, dim3(256), dim3(256), 0, stream,
                     batch, Wl, bl, bias, gam, bet, ws, out);
}

// Round 4
// 233.860 us; speedup vs baseline: 1.7359x; 1.0377x over previous
//
#include <hip/hip_runtime.h>
#include <math.h>

#define NN 50000
#define NE 800000
#define NG 64
#define MAXDEG 64   // max in-degree bound for dense stage; overflow -> atomic fallback

// ---------------- ws layout (float offsets) ----------------
#define WS_C     0                       // 8 floats: [h*4 + {att.Wl, att.Wr, att.We, att.B}]
#define WS_ACC   16                      // 4*NN floats: {den0,den1,t10,t11} per node (float4)
#define WS_BNSUM (WS_ACC + 4*NN)         // 128
#define WS_BNSQ  (WS_BNSUM + 128)        // 128
#define WS_CNT   (WS_BNSQ + 128)         // NN u32
#define WS_STAGE (WS_CNT + NN)           // MAXDEG*NN float4, [slot][node] dense grid
#define WS_END   (WS_STAGE + 4*MAXDEG*NN)
#define WS_NEED_BYTES ((size_t)WS_END * 4 + 256)

static_assert(((WS_STAGE * 4) % 16) == 0, "stage 16B alignment");
static_assert(NE % 4 == 0, "edge unroll");

// ---------------- k0: init + attention-dot constants ----------------
extern "C" __global__ __launch_bounds__(256)
void k0_init(float* __restrict__ ws,
             const float* __restrict__ att, const float* __restrict__ Wl,
             const float* __restrict__ Wr, const float* __restrict__ We,
             const float* __restrict__ bl, const float* __restrict__ br,
             float* __restrict__ out)
{
  int tid = blockIdx.x * 256 + threadIdx.x;
  int nt = gridDim.x * 256;
  for (int i = tid; i < 4 * NN; i += nt) ws[WS_ACC + i] = 0.f;
  for (int i = tid; i < 256; i += nt) ws[WS_BNSUM + i] = 0.f;
  for (int i = tid; i < NG * 128; i += nt) out[i] = 0.f;
  unsigned* cnt = (unsigned*)(ws + WS_CNT);
  for (int i = tid; i < NN; i += nt) cnt[i] = 0u;
  if (blockIdx.x == 0) {
    __shared__ float red[4][256];
    int t = threadIdx.x;                    // t = h*128 + d
    float a = att[t];
    red[0][t] = a * Wl[t];
    red[1][t] = a * Wr[t];
    red[2][t] = a * We[t];
    red[3][t] = a * (bl[t] + br[t]);
    __syncthreads();
    if (t < 8) {
      int k = t >> 1, h = t & 1;
      float s = 0.f;
      for (int d = 0; d < 128; ++d) s += red[k][h * 128 + d];
      ws[WS_C + h * 4 + k] = s;
    }
  }
}

// ---------------- shared score machinery ----------------
// score_h = 0.6*(C·[xs,xd,ae,1]) + 0.4*Σ_d att_d*|Wl_d*xs + Wr_d*xd + We_d*ae + B_d|
#define STEP(wl_, wr_, we_, bb_, at_, xs_, xd_, ae_, acc_)                 \
  { float tt = fmaf(we_, ae_, bb_); tt = fmaf(wr_, xd_, tt);               \
    tt = fmaf(wl_, xs_, tt); acc_ = fmaf(fabsf(tt), at_, acc_); }

#define STEP4(c, q0, q1, q2, q3)                                           \
  STEP(wl.c, wr.c, we.c, bb.c, at.c, xs0, xd0, ae0, q0)                    \
  STEP(wl.c, wr.c, we.c, bb.c, at.c, xs1, xd1, ae1, q1)                    \
  STEP(wl.c, wr.c, we.c, bb.c, at.c, xs2, xd2, ae2, q2)                    \
  STEP(wl.c, wr.c, we.c, bb.c, at.c, xs3, xd3, ae3, q3)

#define SCORE_PREAMBLE                                                     \
  __shared__ __align__(16) float sWl[256], sWr[256], sWe[256], sB[256], sAt[256]; \
  { int t = threadIdx.x;                                                   \
    sWl[t] = Wl[t]; sWr[t] = Wr[t]; sWe[t] = We[t];                        \
    sB[t] = bl[t] + br[t]; sAt[t] = att[t]; }                              \
  __syncthreads();                                                         \
  int base = (blockIdx.x * 256 + threadIdx.x) * 4;                         \
  if (base >= NE) return;                                                  \
  int4 s4 = *(const int4*)&ei[base];                                       \
  int4 dd4 = *(const int4*)&ei[NE + base];                                 \
  float4 ae4 = *(const float4*)&eattr[base];                               \
  float xs0 = x[s4.x], xs1 = x[s4.y], xs2 = x[s4.z], xs3 = x[s4.w];        \
  float xd0 = x[dd4.x], xd1 = x[dd4.y], xd2 = x[dd4.z], xd3 = x[dd4.w];    \
  float ae0 = ae4.x, ae1 = ae4.y, ae2 = ae4.z, ae3 = ae4.w;                \
  float a00 = 0.f, a01 = 0.f, a02 = 0.f, a03 = 0.f;                        \
  float a10 = 0.f, a11 = 0.f, a12 = 0.f, a13 = 0.f;                        \
  _Pragma("unroll 2")                                                      \
  for (int j = 0; j < 128; j += 4) {                                       \
    float4 wl = *(const float4*)&sWl[j];                                   \
    float4 wr = *(const float4*)&sWr[j];                                   \
    float4 we = *(const float4*)&sWe[j];                                   \
    float4 bb = *(const float4*)&sB[j];                                    \
    float4 at = *(const float4*)&sAt[j];                                   \
    STEP4(x, a00, a01, a02, a03)                                           \
    STEP4(y, a00, a01, a02, a03)                                           \
    STEP4(z, a00, a01, a02, a03)                                           \
    STEP4(w, a00, a01, a02, a03)                                           \
  }                                                                        \
  _Pragma("unroll 2")                                                      \
  for (int j = 128; j < 256; j += 4) {                                     \
    float4 wl = *(const float4*)&sWl[j];                                   \
    float4 wr = *(const float4*)&sWr[j];                                   \
    float4 we = *(const float4*)&sWe[j];                                   \
    float4 bb = *(const float4*)&sB[j];                                    \
    float4 at = *(const float4*)&sAt[j];                                   \
    STEP4(x, a10, a11, a12, a13)                                           \
    STEP4(y, a10, a11, a12, a13)                                           \
    STEP4(z, a10, a11, a12, a13)                                           \
    STEP4(w, a10, a11, a12, a13)                                           \
  }                                                                        \
  float4 c0 = *(const float4*)&ws[WS_C];                                   \
  float4 c1 = *(const float4*)&ws[WS_C + 4];

#define SCORES(xs_, xd_, ae_, accA, accB, out0, out1)                      \
  { float lin0 = fmaf(c0.x, xs_, fmaf(c0.y, xd_, fmaf(c0.z, ae_, c0.w))); \
    out0 = fmaf(0.4f, accA, 0.6f * lin0);                                  \
    float lin1 = fmaf(c1.x, xs_, fmaf(c1.y, xd_, fmaf(c1.z, ae_, c1.w))); \
    out1 = fmaf(0.4f, accB, 0.6f * lin1); }

// ---------------- ke: fused score+exp, slot atomic, dense-stage scatter ----------------
extern "C" __global__ __launch_bounds__(256)
void ke_edge(const int* __restrict__ ei, const float* __restrict__ x,
             const float* __restrict__ eattr,
             const float* __restrict__ Wl, const float* __restrict__ Wr,
             const float* __restrict__ We, const float* __restrict__ bl,
             const float* __restrict__ br, const float* __restrict__ att,
             float* __restrict__ ws)
{
  SCORE_PREAMBLE
  unsigned* cnt = (unsigned*)(ws + WS_CNT);
  float4* stage = (float4*)(ws + WS_STAGE);
  float* acc = ws + WS_ACC;
  float s0, s1;
#define EPI(xs_, xd_, ae_, accA, accB, dsti)                               \
  { SCORES(xs_, xd_, ae_, accA, accB, s0, s1)                              \
    float e0 = __expf(s0), e1 = __expf(s1);                                \
    unsigned sl = atomicAdd(&cnt[dsti], 1u);                               \
    if (sl < MAXDEG) {                                                     \
      stage[sl * NN + dsti] = make_float4(e0, e1, e0 * xs_, e1 * xs_);     \
    } else {                                                               \
      float* a = &acc[4 * dsti];                                           \
      atomicAdd(a + 0, e0); atomicAdd(a + 1, e1);                          \
      atomicAdd(a + 2, e0 * xs_); atomicAdd(a + 3, e1 * xs_);              \
    } }
  EPI(xs0, xd0, ae0, a00, a10, dd4.x)
  EPI(xs1, xd1, ae1, a01, a11, dd4.y)
  EPI(xs2, xd2, ae2, a02, a12, dd4.z)
  EPI(xs3, xd3, ae3, a03, a13, dd4.w)
#undef EPI
}

// ---------------- kf: lane-per-node gather over dense stage (coalesced, 0 atomics) ----------------
extern "C" __global__ __launch_bounds__(256)
void kf_gather(float* __restrict__ ws)
{
  int n = blockIdx.x * 256 + threadIdx.x;
  if (n >= NN) return;
  const unsigned* cnt = (const unsigned*)(ws + WS_CNT);
  const float4* stage = (const float4*)(ws + WS_STAGE);
  unsigned c = cnt[n];
  unsigned cc = c < MAXDEG ? c : MAXDEG;
  float4 a = *(const float4*)&ws[WS_ACC + 4 * n];  // overflow-fallback contributions
  float den0 = a.x, den1 = a.y, t10 = a.z, t11 = a.w;
  for (unsigned j = 0; j < cc; ++j) {
    float4 p = stage[j * NN + n];
    den0 += p.x; den1 += p.y; t10 += p.z; t11 += p.w;
  }
  *(float4*)&ws[WS_ACC + 4 * n] = make_float4(den0, den1, t10, t11);
}

// ---------------- fallback: fused score + exp + 4 atomics/edge (small ws) ----------------
extern "C" __global__ __launch_bounds__(256)
void k12f(const int* __restrict__ ei, const float* __restrict__ x,
          const float* __restrict__ eattr,
          const float* __restrict__ Wl, const float* __restrict__ Wr,
          const float* __restrict__ We, const float* __restrict__ bl,
          const float* __restrict__ br, const float* __restrict__ att,
          float* __restrict__ ws)
{
  SCORE_PREAMBLE
  float* acc = ws + WS_ACC;
  float s0, s1;
#define EPI2(xs_, xd_, ae_, accA, accB, dsti)                              \
  { SCORES(xs_, xd_, ae_, accA, accB, s0, s1)                              \
    float e0 = __expf(s0), e1 = __expf(s1);                                \
    float* a = &acc[4 * dsti];                                             \
    atomicAdd(a + 0, e0); atomicAdd(a + 1, e1);                            \
    atomicAdd(a + 2, e0 * xs_); atomicAdd(a + 3, e1 * xs_); }
  EPI2(xs0, xd0, ae0, a00, a10, dd4.x)
  EPI2(xs1, xd1, ae1, a01, a11, dd4.y)
  EPI2(xs2, xd2, ae2, a02, a12, dd4.z)
  EPI2(xs3, xd3, ae3, a03, a13, dd4.w)
#undef EPI2
}

// ---------------- node output from the 4 per-node scalars ----------------
__device__ __forceinline__ float node_out4(float4 a, float wl0, float wl1,
                                           float b0, float b1, float bs)
{
  float r0 = 1.f / (a.x + 1e-16f);
  float r1 = 1.f / (a.y + 1e-16f);
  return 0.5f * (fmaf(wl0, a.z * r0, b0 * (a.x * r0)) +
                 fmaf(wl1, a.w * r1, b1 * (a.y * r1))) + bs;
}

// ---------------- k3: BN statistics ----------------
extern "C" __global__ __launch_bounds__(256)
void k3_stats(const float* __restrict__ Wl, const float* __restrict__ bl,
              const float* __restrict__ bias, float* __restrict__ ws)
{
  int d = threadIdx.x & 127;
  int row = threadIdx.x >> 7;
  float wl0 = Wl[d], wl1 = Wl[128 + d];
  float b0 = bl[d], b1 = bl[128 + d];
  float bs = bias[d];
  float sum = 0.f, sq = 0.f;
  for (int n = blockIdx.x * 2 + row; n < NN; n += gridDim.x * 2) {
    float4 a = *(const float4*)&ws[WS_ACC + 4 * n];
    float o = node_out4(a, wl0, wl1, b0, b1, bs);
    sum += o;
    sq = fmaf(o, o, sq);
  }
  __shared__ float l1[256], l2[256];
  l1[threadIdx.x] = sum; l2[threadIdx.x] = sq;
  __syncthreads();
  if (row == 0) {
    atomicAdd(&ws[WS_BNSUM + d], l1[d] + l1[128 + d]);
    atomicAdd(&ws[WS_BNSQ + d], l2[d] + l2[128 + d]);
  }
}

// ---------------- k4: BN apply + leaky_relu + graph pooling ----------------
extern "C" __global__ __launch_bounds__(256)
void k4_pool(const int* __restrict__ batch,
             const float* __restrict__ Wl, const float* __restrict__ bl,
             const float* __restrict__ bias, const float* __restrict__ gamma,
             const float* __restrict__ beta,
             float* __restrict__ ws, float* __restrict__ out)
{
  const int CHUNK = (NN + (int)gridDim.x - 1) / (int)gridDim.x;
  int n0 = blockIdx.x * CHUNK;
  if (n0 >= NN) return;
  int n1 = n0 + CHUNK; if (n1 > NN) n1 = NN;
  int d = threadIdx.x & 127;
  int row = threadIdx.x >> 7;
  const float invN = 1.f / (float)NN;
  float mean = ws[WS_BNSUM + d] * invN;
  float var = fmaf(ws[WS_BNSQ + d], invN, -mean * mean);
  float scale = gamma[d] * rsqrtf(var + 1e-5f);
  float shift = fmaf(-mean, scale, beta[d]);
  float wl0 = Wl[d], wl1 = Wl[128 + d];
  float b0 = bl[d], b1 = bl[128 + d];
  float bs = bias[d];
  __shared__ float pool[4][128];
  for (int i = threadIdx.x; i < 512; i += 256) ((float*)pool)[i] = 0.f;
  __syncthreads();
  int g0 = batch[n0];
  for (int n = n0 + row; n < n1; n += 2) {
    float4 a = *(const float4*)&ws[WS_ACC + 4 * n];
    float o = node_out4(a, wl0, wl1, b0, b1, bs);
    float v = fmaf(o, scale, shift);
    v = v > 0.f ? v : 0.01f * v;
    int g = batch[n];
    int slot = g - g0;                    // >= 0: batch is sorted
    if (slot < 4) atomicAdd(&pool[slot][d], v);
    else atomicAdd(&out[g * 128 + d], v); // >4 graphs in chunk: rare fallback
  }
  __syncthreads();
  for (int i = threadIdx.x; i < 512; i += 256) {
    int slot = i >> 7, dd = i & 127;
    int g = g0 + slot;
    float v = pool[slot][dd];
    if (g < NG && v != 0.f) atomicAdd(&out[g * 128 + dd], v);
  }
}

extern "C" void kernel_launch(void* const* d_in, const int* in_sizes, int n_in,
                              void* d_out, int out_size, void* d_ws, size_t ws_size,
                              hipStream_t stream) {
  const float* x     = (const float*)d_in[0];
  const int*   ei    = (const int*)d_in[1];
  const float* eattr = (const float*)d_in[2];
  const int*   batch = (const int*)d_in[3];
  const float* Wl    = (const float*)d_in[4];
  const float* bl    = (const float*)d_in[5];
  const float* Wr    = (const float*)d_in[6];
  const float* br    = (const float*)d_in[7];
  const float* We    = (const float*)d_in[8];
  const float* att   = (const float*)d_in[9];
  const float* bias  = (const float*)d_in[10];
  const float* gam   = (const float*)d_in[11];
  const float* bet   = (const float*)d_in[12];
  float* ws  = (float*)d_ws;
  float* out = (float*)d_out;

  const bool dense = (ws_size >= WS_NEED_BYTES);
  const int EB = (NE / 4 + 255) / 256;   // edge blocks (4 edges/thread)

  hipLaunchKernelGGL(k0_init, dim3(128), dim3(256), 0, stream,
                     ws, att, Wl, Wr, We, bl, br, out);
  if (dense) {
    hipLaunchKernelGGL(ke_edge, dim3(EB), dim3(256), 0, stream,
                       ei, x, eattr, Wl, Wr, We, bl, br, att, ws);
    hipLaunchKernelGGL(kf_gather, dim3((NN + 255) / 256), dim3(256), 0, stream, ws);
  } else {
    hipLaunchKernelGGL(k12f, dim3(EB), dim3(256), 0, stream,
                       ei, x, eattr, Wl, Wr, We, bl, br, att, ws);
  }
  hipLaunchKernelGGL(k3_stats, dim3(256), dim3(256), 0, stream,
                     Wl, bl, bias, ws);
  hipLaunchKernelGGL(k4_pool, dim3(256), dim3(256), 0, stream,
                     batch, Wl, bl, bias, gam, bet, ws, out);
}

// Round 5
// 228.955 us; speedup vs baseline: 1.7731x; 1.0214x over previous
//
#include <hip/hip_runtime.h>
#include <math.h>

#define NN 50000
#define NE 800000
#define NG 64

// ---------------- ws layout (float offsets) ----------------
#define WS_C     0                       // 8 floats: [h*4 + {att.Wl, att.Wr, att.We, att.B}]
#define WS_ACC   16                      // 4*NN floats: {den0,den1,t10,t11} per node (float4)
#define WS_BNSUM (WS_ACC + 4*NN)         // 128
#define WS_BNSQ  (WS_BNSUM + 128)        // 128
#define WS_HEAD  (WS_BNSQ + 128)         // NN u32 list heads (0xFFFFFFFF = end)
#define WS_STAGE (WS_HEAD + NN)          // NE float4 = {e0, e1, x_src, prev_bits}
#define WS_END   (WS_STAGE + 4*NE)
#define WS_NEED_BYTES ((size_t)WS_END * 4 + 256)

static_assert(((WS_STAGE * 4) % 16) == 0, "stage 16B alignment");
static_assert(NE % 4 == 0, "edge unroll");

// ---------------- k0: init + attention-dot constants ----------------
extern "C" __global__ __launch_bounds__(256)
void k0_init(float* __restrict__ ws,
             const float* __restrict__ att, const float* __restrict__ Wl,
             const float* __restrict__ Wr, const float* __restrict__ We,
             const float* __restrict__ bl, const float* __restrict__ br,
             float* __restrict__ out)
{
  int tid = blockIdx.x * 256 + threadIdx.x;
  int nt = gridDim.x * 256;
  for (int i = tid; i < 4 * NN; i += nt) ws[WS_ACC + i] = 0.f;   // fallback path needs zeros
  for (int i = tid; i < 256; i += nt) ws[WS_BNSUM + i] = 0.f;
  for (int i = tid; i < NG * 128; i += nt) out[i] = 0.f;
  unsigned* head = (unsigned*)(ws + WS_HEAD);
  for (int i = tid; i < NN; i += nt) head[i] = 0xFFFFFFFFu;
  if (blockIdx.x == 0) {
    __shared__ float red[4][256];
    int t = threadIdx.x;                    // t = h*128 + d
    float a = att[t];
    red[0][t] = a * Wl[t];
    red[1][t] = a * Wr[t];
    red[2][t] = a * We[t];
    red[3][t] = a * (bl[t] + br[t]);
    __syncthreads();
    if (t < 8) {
      int k = t >> 1, h = t & 1;
      float s = 0.f;
      for (int d = 0; d < 128; ++d) s += red[k][h * 128 + d];
      ws[WS_C + h * 4 + k] = s;
    }
  }
}

// ---------------- shared score machinery ----------------
// score_h = 0.6*(C·[xs,xd,ae,1]) + 0.4*Σ_d att_d*|Wl_d*xs + Wr_d*xd + We_d*ae + B_d|
#define STEP(wl_, wr_, we_, bb_, at_, xs_, xd_, ae_, acc_)                 \
  { float tt = fmaf(we_, ae_, bb_); tt = fmaf(wr_, xd_, tt);               \
    tt = fmaf(wl_, xs_, tt); acc_ = fmaf(fabsf(tt), at_, acc_); }

#define STEP4(c, q0, q1, q2, q3)                                           \
  STEP(wl.c, wr.c, we.c, bb.c, at.c, xs0, xd0, ae0, q0)                    \
  STEP(wl.c, wr.c, we.c, bb.c, at.c, xs1, xd1, ae1, q1)                    \
  STEP(wl.c, wr.c, we.c, bb.c, at.c, xs2, xd2, ae2, q2)                    \
  STEP(wl.c, wr.c, we.c, bb.c, at.c, xs3, xd3, ae3, q3)

#define SCORE_PREAMBLE                                                     \
  __shared__ __align__(16) float sWl[256], sWr[256], sWe[256], sB[256], sAt[256]; \
  { int t = threadIdx.x;                                                   \
    sWl[t] = Wl[t]; sWr[t] = Wr[t]; sWe[t] = We[t];                        \
    sB[t] = bl[t] + br[t]; sAt[t] = att[t]; }                              \
  __syncthreads();                                                         \
  int base = (blockIdx.x * 256 + threadIdx.x) * 4;                         \
  if (base >= NE) return;                                                  \
  int4 s4 = *(const int4*)&ei[base];                                       \
  int4 dd4 = *(const int4*)&ei[NE + base];                                 \
  float4 ae4 = *(const float4*)&eattr[base];                               \
  float xs0 = x[s4.x], xs1 = x[s4.y], xs2 = x[s4.z], xs3 = x[s4.w];        \
  float xd0 = x[dd4.x], xd1 = x[dd4.y], xd2 = x[dd4.z], xd3 = x[dd4.w];    \
  float ae0 = ae4.x, ae1 = ae4.y, ae2 = ae4.z, ae3 = ae4.w;                \
  float a00 = 0.f, a01 = 0.f, a02 = 0.f, a03 = 0.f;                        \
  float a10 = 0.f, a11 = 0.f, a12 = 0.f, a13 = 0.f;                        \
  _Pragma("unroll 2")                                                      \
  for (int j = 0; j < 128; j += 4) {                                       \
    float4 wl = *(const float4*)&sWl[j];                                   \
    float4 wr = *(const float4*)&sWr[j];                                   \
    float4 we = *(const float4*)&sWe[j];                                   \
    float4 bb = *(const float4*)&sB[j];                                    \
    float4 at = *(const float4*)&sAt[j];                                   \
    STEP4(x, a00, a01, a02, a03)                                           \
    STEP4(y, a00, a01, a02, a03)                                           \
    STEP4(z, a00, a01, a02, a03)                                           \
    STEP4(w, a00, a01, a02, a03)                                           \
  }                                                                        \
  _Pragma("unroll 2")                                                      \
  for (int j = 128; j < 256; j += 4) {                                     \
    float4 wl = *(const float4*)&sWl[j];                                   \
    float4 wr = *(const float4*)&sWr[j];                                   \
    float4 we = *(const float4*)&sWe[j];                                   \
    float4 bb = *(const float4*)&sB[j];                                    \
    float4 at = *(const float4*)&sAt[j];                                   \
    STEP4(x, a10, a11, a12, a13)                                           \
    STEP4(y, a10, a11, a12, a13)                                           \
    STEP4(z, a10, a11, a12, a13)                                           \
    STEP4(w, a10, a11, a12, a13)                                           \
  }                                                                        \
  float4 c0 = *(const float4*)&ws[WS_C];                                   \
  float4 c1 = *(const float4*)&ws[WS_C + 4];

#define SCORES(xs_, xd_, ae_, accA, accB, out0, out1)                      \
  { float lin0 = fmaf(c0.x, xs_, fmaf(c0.y, xd_, fmaf(c0.z, ae_, c0.w))); \
    out0 = fmaf(0.4f, accA, 0.6f * lin0);                                  \
    float lin1 = fmaf(c1.x, xs_, fmaf(c1.y, xd_, fmaf(c1.z, ae_, c1.w))); \
    out1 = fmaf(0.4f, accB, 0.6f * lin1); }

// ---------------- ke: fused score+exp, linked-list staging ----------------
// 1 random op/edge (atomicExch on head[dst]); payload+prev = one coalesced float4.
extern "C" __global__ __launch_bounds__(256)
void ke_edge(const int* __restrict__ ei, const float* __restrict__ x,
             const float* __restrict__ eattr,
             const float* __restrict__ Wl, const float* __restrict__ Wr,
             const float* __restrict__ We, const float* __restrict__ bl,
             const float* __restrict__ br, const float* __restrict__ att,
             float* __restrict__ ws)
{
  SCORE_PREAMBLE
  unsigned* head = (unsigned*)(ws + WS_HEAD);
  float4* stage = (float4*)(ws + WS_STAGE);
  float s0, s1;
#define EPI(xs_, xd_, ae_, accA, accB, dsti, eoff)                         \
  { SCORES(xs_, xd_, ae_, accA, accB, s0, s1)                              \
    float e0 = __expf(s0), e1 = __expf(s1);                                \
    unsigned prev = atomicExch(&head[dsti], (unsigned)(base + eoff));      \
    stage[base + eoff] = make_float4(e0, e1, xs_, __uint_as_float(prev)); }
  EPI(xs0, xd0, ae0, a00, a10, dd4.x, 0)
  EPI(xs1, xd1, ae1, a01, a11, dd4.y, 1)
  EPI(xs2, xd2, ae2, a02, a12, dd4.z, 2)
  EPI(xs3, xd3, ae3, a03, a13, dd4.w, 3)
#undef EPI
}

// ---------------- kf: per-node list walk (0 atomics) ----------------
extern "C" __global__ __launch_bounds__(256)
void kf_gather(float* __restrict__ ws)
{
  int n = blockIdx.x * 256 + threadIdx.x;
  if (n >= NN) return;
  const unsigned* head = (const unsigned*)(ws + WS_HEAD);
  const float4* stage = (const float4*)(ws + WS_STAGE);
  unsigned p = head[n];
  float den0 = 0.f, den1 = 0.f, t10 = 0.f, t11 = 0.f;
  while (p != 0xFFFFFFFFu) {
    float4 q = stage[p];
    den0 += q.x; den1 += q.y;
    t10 = fmaf(q.x, q.z, t10);
    t11 = fmaf(q.y, q.z, t11);
    p = __float_as_uint(q.w);
  }
  *(float4*)&ws[WS_ACC + 4 * n] = make_float4(den0, den1, t10, t11);
}

// ---------------- fallback: fused score + exp + 4 atomics/edge (small ws) ----------------
extern "C" __global__ __launch_bounds__(256)
void k12f(const int* __restrict__ ei, const float* __restrict__ x,
          const float* __restrict__ eattr,
          const float* __restrict__ Wl, const float* __restrict__ Wr,
          const float* __restrict__ We, const float* __restrict__ bl,
          const float* __restrict__ br, const float* __restrict__ att,
          float* __restrict__ ws)
{
  SCORE_PREAMBLE
  float* acc = ws + WS_ACC;
  float s0, s1;
#define EPI2(xs_, xd_, ae_, accA, accB, dsti)                              \
  { SCORES(xs_, xd_, ae_, accA, accB, s0, s1)                              \
    float e0 = __expf(s0), e1 = __expf(s1);                                \
    float* a = &acc[4 * dsti];                                             \
    atomicAdd(a + 0, e0); atomicAdd(a + 1, e1);                            \
    atomicAdd(a + 2, e0 * xs_); atomicAdd(a + 3, e1 * xs_); }
  EPI2(xs0, xd0, ae0, a00, a10, dd4.x)
  EPI2(xs1, xd1, ae1, a01, a11, dd4.y)
  EPI2(xs2, xd2, ae2, a02, a12, dd4.z)
  EPI2(xs3, xd3, ae3, a03, a13, dd4.w)
#undef EPI2
}

// ---------------- node output from the 4 per-node scalars ----------------
__device__ __forceinline__ float node_out4(float4 a, float wl0, float wl1,
                                           float b0, float b1, float bs)
{
  float r0 = 1.f / (a.x + 1e-16f);
  float r1 = 1.f / (a.y + 1e-16f);
  return 0.5f * (fmaf(wl0, a.z * r0, b0 * (a.x * r0)) +
                 fmaf(wl1, a.w * r1, b1 * (a.y * r1))) + bs;
}

// ---------------- k3: BN statistics ----------------
extern "C" __global__ __launch_bounds__(256)
void k3_stats(const float* __restrict__ Wl, const float* __restrict__ bl,
              const float* __restrict__ bias, float* __restrict__ ws)
{
  int d = threadIdx.x & 127;
  int row = threadIdx.x >> 7;
  float wl0 = Wl[d], wl1 = Wl[128 + d];
  float b0 = bl[d], b1 = bl[128 + d];
  float bs = bias[d];
  float sum = 0.f, sq = 0.f;
  for (int n = blockIdx.x * 2 + row; n < NN; n += gridDim.x * 2) {
    float4 a = *(const float4*)&ws[WS_ACC + 4 * n];
    float o = node_out4(a, wl0, wl1, b0, b1, bs);
    sum += o;
    sq = fmaf(o, o, sq);
  }
  __shared__ float l1[256], l2[256];
  l1[threadIdx.x] = sum; l2[threadIdx.x] = sq;
  __syncthreads();
  if (row == 0) {
    atomicAdd(&ws[WS_BNSUM + d], l1[d] + l1[128 + d]);
    atomicAdd(&ws[WS_BNSQ + d], l2[d] + l2[128 + d]);
  }
}

// ---------------- k4: BN apply + leaky_relu + graph pooling ----------------
extern "C" __global__ __launch_bounds__(256)
void k4_pool(const int* __restrict__ batch,
             const float* __restrict__ Wl, const float* __restrict__ bl,
             const float* __restrict__ bias, const float* __restrict__ gamma,
             const float* __restrict__ beta,
             float* __restrict__ ws, float* __restrict__ out)
{
  const int CHUNK = (NN + (int)gridDim.x - 1) / (int)gridDim.x;
  int n0 = blockIdx.x * CHUNK;
  if (n0 >= NN) return;
  int n1 = n0 + CHUNK; if (n1 > NN) n1 = NN;
  int d = threadIdx.x & 127;
  int row = threadIdx.x >> 7;
  const float invN = 1.f / (float)NN;
  float mean = ws[WS_BNSUM + d] * invN;
  float var = fmaf(ws[WS_BNSQ + d], invN, -mean * mean);
  float scale = gamma[d] * rsqrtf(var + 1e-5f);
  float shift = fmaf(-mean, scale, beta[d]);
  float wl0 = Wl[d], wl1 = Wl[128 + d];
  float b0 = bl[d], b1 = bl[128 + d];
  float bs = bias[d];
  __shared__ float pool[4][128];
  for (int i = threadIdx.x; i < 512; i += 256) ((float*)pool)[i] = 0.f;
  __syncthreads();
  int g0 = batch[n0];
  for (int n = n0 + row; n < n1; n += 2) {
    float4 a = *(const float4*)&ws[WS_ACC + 4 * n];
    float o = node_out4(a, wl0, wl1, b0, b1, bs);
    float v = fmaf(o, scale, shift);
    v = v > 0.f ? v : 0.01f * v;
    int g = batch[n];
    int slot = g - g0;                    // >= 0: batch is sorted
    if (slot < 4) atomicAdd(&pool[slot][d], v);
    else atomicAdd(&out[g * 128 + d], v); // >4 graphs in chunk: rare fallback
  }
  __syncthreads();
  for (int i = threadIdx.x; i < 512; i += 256) {
    int slot = i >> 7, dd = i & 127;
    int g = g0 + slot;
    float v = pool[slot][dd];
    if (g < NG && v != 0.f) atomicAdd(&out[g * 128 + dd], v);
  }
}

extern "C" void kernel_launch(void* const* d_in, const int* in_sizes, int n_in,
                              void* d_out, int out_size, void* d_ws, size_t ws_size,
                              hipStream_t stream) {
  const float* x     = (const float*)d_in[0];
  const int*   ei    = (const int*)d_in[1];
  const float* eattr = (const float*)d_in[2];
  const int*   batch = (const int*)d_in[3];
  const float* Wl    = (const float*)d_in[4];
  const float* bl    = (const float*)d_in[5];
  const float* Wr    = (const float*)d_in[6];
  const float* br    = (const float*)d_in[7];
  const float* We    = (const float*)d_in[8];
  const float* att   = (const float*)d_in[9];
  const float* bias  = (const float*)d_in[10];
  const float* gam   = (const float*)d_in[11];
  const float* bet   = (const float*)d_in[12];
  float* ws  = (float*)d_ws;
  float* out = (float*)d_out;

  const bool dense = (ws_size >= WS_NEED_BYTES);
  const int EB = (NE / 4 + 255) / 256;   // edge blocks (4 edges/thread)

  hipLaunchKernelGGL(k0_init, dim3(128), dim3(256), 0, stream,
                     ws, att, Wl, Wr, We, bl, br, out);
  if (dense) {
    hipLaunchKernelGGL(ke_edge, dim3(EB), dim3(256), 0, stream,
                       ei, x, eattr, Wl, Wr, We, bl, br, att, ws);
    hipLaunchKernelGGL(kf_gather, dim3((NN + 255) / 256), dim3(256), 0, stream, ws);
  } else {
    hipLaunchKernelGGL(k12f, dim3(EB), dim3(256), 0, stream,
                       ei, x, eattr, Wl, Wr, We, bl, br, att, ws);
  }
  hipLaunchKernelGGL(k3_stats, dim3(256), dim3(256), 0, stream,
                     Wl, bl, bias, ws);
  hipLaunchKernelGGL(k4_pool, dim3(256), dim3(256), 0, stream,
                     batch, Wl, bl, bias, gam, bet, ws, out);
}